// Round 9
// baseline (3528.125 us; speedup 1.0000x reference)
//
#include <hip/hip_runtime.h>

#define NB 128      // batch
#define NT 8192     // time steps
#define NS 128      // states
#define NE 6        // alphabet
#define ROWS 16     // batch rows per block
#define WAVES 8     // 512 threads; wave w owns STATES [16w, 16w+16)
#define NMAT 7      // C_0..C_5 = A*diag(e_o)*A (bf16), C_6 = A (bf16)
#define CT_BYTES (NMAT * NS * NS * 2)    // 229376

typedef __attribute__((ext_vector_type(8))) short bf16x8;   // 8 bf16 (4 VGPRs)
typedef __attribute__((ext_vector_type(4))) float f32x4;    // MFMA accumulator
typedef __attribute__((ext_vector_type(4))) int   int32x4;

#define MFMA __builtin_amdgcn_mfma_f32_16x16x32_bf16

// fp32 -> bf16, round-to-nearest-even
__device__ __forceinline__ ushort f2bf(float v) {
    unsigned u = __float_as_uint(v);
    u += 0x7fffu + ((u >> 16) & 1u);
    return (ushort)(u >> 16);
}

// alpha LDS layout: row-major [batch b][state s], bf16, byte-XOR-swizzled by
// batch row: byte ^= (b&7)<<4. Preserves 16B alignment of b128 reads and 8B
// alignment of b64 writes (flips byte bits 4-6 within the 256B row).
#define ASWZ(b, byteoff) ((byteoff) ^ (((b) & 7) << 4))

// ---------------------------------------------------------------------------
// Precompute Ct (bf16, transposed: Ct[(m*NS + col)*NS + k] = C_m[k][col]).
// C_m = A * diag(Bm[:,m]) * A for m<6;  C_6 = A.  Grid (7, 4) x 128 threads.
// ---------------------------------------------------------------------------
__global__ void __launch_bounds__(128, 1)
hmm_precompute_kernel(const float* __restrict__ A, const float* __restrict__ Bm,
                      ushort* __restrict__ Ct)
{
    __shared__ float Af[NS * NS];   // 64 KB
    __shared__ float wA[NS * NS];   // 64 KB
    const int s  = threadIdx.x;
    const int m  = blockIdx.x;
    const int ig = blockIdx.y;      // k-row group [ig*32, ig*32+32)

    for (int r = 0; r < NS; ++r) Af[r * NS + s] = A[r * NS + s];
    __syncthreads();

    if (m < 6) {
        for (int k = 0; k < NS; ++k)
            wA[k * NS + s] = Bm[k * NE + m] * Af[k * NS + s];
        __syncthreads();
        for (int i0 = ig * 32; i0 < ig * 32 + 32; i0 += 4) {
            float a0 = 0.f, a1 = 0.f, a2 = 0.f, a3 = 0.f;
            for (int k = 0; k < NS; ++k) {
                const float wv = wA[k * NS + s];
                a0 = fmaf(Af[(i0 + 0) * NS + k], wv, a0);
                a1 = fmaf(Af[(i0 + 1) * NS + k], wv, a1);
                a2 = fmaf(Af[(i0 + 2) * NS + k], wv, a2);
                a3 = fmaf(Af[(i0 + 3) * NS + k], wv, a3);
            }
            Ct[(m * NS + s) * NS + i0 + 0] = f2bf(a0);
            Ct[(m * NS + s) * NS + i0 + 1] = f2bf(a1);
            Ct[(m * NS + s) * NS + i0 + 2] = f2bf(a2);
            Ct[(m * NS + s) * NS + i0 + 3] = f2bf(a3);
        }
    } else {
        for (int i = ig * 32; i < ig * 32 + 32; ++i)
            Ct[(6 * NS + s) * NS + i] = f2bf(Af[i * NS + s]);
    }
}

// ---------------------------------------------------------------------------
// Operand-swapped pair-step kernel: D = mfma(A = C_s^T, B = alpha^T).
// D: col = li = BATCH, row = state 16w + 4h + reg. So per lane: symbols are
// per-lane scalars (packed byte), emissions are registers, alpha write is one
// packed b64. 512 threads (8 waves), 16 batch rows per block.
// ---------------------------------------------------------------------------
__global__ void __launch_bounds__(512, 1)
hmm_swap_kernel(const int* __restrict__ obs, const float* __restrict__ I,
                const float* __restrict__ Bm, const ushort* __restrict__ Ct,
                float* __restrict__ out)
{
    __shared__ __align__(16) ushort alds[2][ROWS * NS];   // bf16 alpha, dbuf, swizzled
    __shared__ __align__(8) unsigned char pkb[ROWS * 64]; // packed (o1|o2<<3) per [b][pair]
    __shared__ __align__(16) int obs_lds[ROWS][132];      // raw obs chunk (+overlap)
    __shared__ float part[WAVES][ROWS];                   // per-wave state-partials
    __shared__ float Zs[ROWS];                            // 1/Z per batch row

    const int tid = threadIdx.x;
    const int w   = tid >> 6;       // wave -> states [16w, 16w+16)
    const int l   = tid & 63;
    const int h   = l >> 4;         // quarter-wave
    const int li  = l & 15;         // batch column
    const int cc  = 16 * w + li;    // fragment column index into Ct
    const int brow0 = blockIdx.x * ROWS;

    // ---- A-operand fragments: C_s^T, lane holds C_s[k=32q+8h+j][16w+li] ----
    bf16x8 bfrag[6][4];
#pragma unroll
    for (int s = 0; s < 6; ++s)
#pragma unroll
        for (int q = 0; q < 4; ++q)
            bfrag[s][q] = *(const bf16x8*)(Ct + ((s * NS + cc) * NS + 32 * q + 8 * h));
    bf16x8 afin[4];   // plain A (Ct[6]) for the final odd step
#pragma unroll
    for (int q = 0; q < 4; ++q)
        afin[q] = *(const bf16x8*)(Ct + ((6 * NS + cc) * NS + 32 * q + 8 * h));

    // ---- emissions in registers: er[o][r] = e_o[state 16w+4h+r] ----
    float er[6][4];
#pragma unroll
    for (int o = 0; o < 6; ++o)
#pragma unroll
        for (int r = 0; r < 4; ++r)
            er[o][r] = Bm[(16 * w + 4 * h + r) * NE + o];

    // ---- stage obs chunk 0 (+ overlap entry 128) ----
    {
        const int b = tid >> 5, ii = (tid & 31) * 4;
        *(int32x4*)&obs_lds[b][ii] =
            *(const int32x4*)(obs + (size_t)(brow0 + b) * NT + ii);
        if (tid < ROWS)
            obs_lds[tid][128] = obs[(size_t)(brow0 + tid) * NT + 128];
    }
    __syncthreads();

    // ---- pack pkb + t=0 init (both read obs_lds, write disjoint LDS) ----
    {
        const int b = tid >> 5, pp = (tid & 31) * 2;
        const int a1 = obs_lds[b][2 * pp + 1], a2 = obs_lds[b][2 * pp + 2];
        const int b1 = obs_lds[b][2 * pp + 3], b2 = obs_lds[b][2 * pp + 4];
        ((ushort*)pkb)[b * 32 + (pp >> 1)] =
            (ushort)((a1 | (a2 << 3)) | ((b1 | (b2 << 3)) << 8));

        // t = 0: alpha = I * em_0 (unnormalized), layout [b][s] swizzled
        const int s0 = (tid & 31) * 4;
        const int o0 = obs_lds[b][0];
        uint2 pkd;
        pkd.x = (unsigned)f2bf(I[s0 + 0] * Bm[(s0 + 0) * NE + o0]) |
                ((unsigned)f2bf(I[s0 + 1] * Bm[(s0 + 1) * NE + o0]) << 16);
        pkd.y = (unsigned)f2bf(I[s0 + 2] * Bm[(s0 + 2) * NE + o0]) |
                ((unsigned)f2bf(I[s0 + 3] * Bm[(s0 + 3) * NE + o0]) << 16);
        *(uint2*)((char*)alds[0] + ASWZ(b, b * 256 + s0 * 2)) = pkd;
    }
    __syncthreads();

    float ll  = 0.f;   // valid on tid < ROWS (batch row = tid)
    int   cur = 0;
    int   ps  = 0;     // pair counter (rescale every 16 pairs = 32 steps)
    unsigned long long pk8 = 0;

    for (int c = 0; c < 64; ++c) {
        if (c) {   // next chunk: t in [128c, 128c+128]
            const int b = tid >> 5, ii = (tid & 31) * 4;
            *(int32x4*)&obs_lds[b][ii] =
                *(const int32x4*)(obs + (size_t)(brow0 + b) * NT + 128 * c + ii);
            if (tid < ROWS) {
                const int gi = 128 * c + 128;
                obs_lds[tid][128] = (gi < NT)
                    ? obs[(size_t)(brow0 + tid) * NT + gi] : 0;
            }
            __syncthreads();
            const int pp = (tid & 31) * 2;
            const int a1 = obs_lds[b][2 * pp + 1], a2 = obs_lds[b][2 * pp + 2];
            const int b1 = obs_lds[b][2 * pp + 3], b2 = obs_lds[b][2 * pp + 4];
            ((ushort*)pkb)[b * 32 + (pp >> 1)] =
                (ushort)((a1 | (a2 << 3)) | ((b1 | (b2 << 3)) << 8));
            __syncthreads();
        }
        const int npairs = (c < 63) ? 64 : 63;   // chunk 63: 63 pairs + final single
        for (int p = 0; p < npairs; ++p) {
            if ((p & 7) == 0)   // 8 pairs' symbol bytes in one b64
                pk8 = *(const unsigned long long*)&pkb[li * 64 + p];
            const unsigned sy = (unsigned)(pk8 >> (8 * (p & 7))) & 63u;
            const int o1 = sy & 7, o2 = sy >> 3;

            // B-operand: alpha^T, lane holds alpha[li][k = 32q+8h+j]
            bf16x8 bf[4];
#pragma unroll
            for (int q = 0; q < 4; ++q)
                bf[q] = *(const bf16x8*)((const char*)alds[cur] +
                        ASWZ(li, li * 256 + 64 * q + 16 * h));

            f32x4 acc[6];
#pragma unroll
            for (int s = 0; s < 6; ++s) acc[s] = (f32x4){0.f, 0.f, 0.f, 0.f};
#pragma unroll
            for (int q = 0; q < 4; ++q)
#pragma unroll
                for (int s = 0; s < 6; ++s)
                    acc[s] = MFMA(bfrag[s][q], bf[q], acc[s], 0, 0, 0);

            // select by this lane's o1, apply emission e_{o2}[state] from regs
            float vals[4];
#pragma unroll
            for (int r = 0; r < 4; ++r) {
                float v = acc[0][r];
                v = (o1 == 1) ? acc[1][r] : v;
                v = (o1 == 2) ? acc[2][r] : v;
                v = (o1 == 3) ? acc[3][r] : v;
                v = (o1 == 4) ? acc[4][r] : v;
                v = (o1 == 5) ? acc[5][r] : v;
                float e = er[0][r];
                e = (o2 == 1) ? er[1][r] : e;
                e = (o2 == 2) ? er[2][r] : e;
                e = (o2 == 3) ? er[3][r] : e;
                e = (o2 == 4) ? er[4][r] : e;
                e = (o2 == 5) ? er[5][r] : e;
                vals[r] = v * e;
            }

            ++ps;
            if ((ps & 15) == 0) {   // rescale (block-uniform branch)
                float sm = (vals[0] + vals[1]) + (vals[2] + vals[3]);
                sm += __shfl_xor(sm, 16);
                sm += __shfl_xor(sm, 32);        // sum over h: wave's 16 states
                if (l < 16) part[w][li] = sm;
                __syncthreads();
                if (tid < ROWS) {
                    float Z = 0.f;
#pragma unroll
                    for (int ww = 0; ww < WAVES; ++ww) Z += part[ww][tid];
                    ll += logf(Z);
                    Zs[tid] = 1.0f / Z;
                }
                __syncthreads();
                const float zi = Zs[li];
#pragma unroll
                for (int r = 0; r < 4; ++r) vals[r] *= zi;
            }

            // write alpha_new[li][16w+4h+0..3]: one packed b64, swizzled
            uint2 pkd;
            pkd.x = (unsigned)f2bf(vals[0]) | ((unsigned)f2bf(vals[1]) << 16);
            pkd.y = (unsigned)f2bf(vals[2]) | ((unsigned)f2bf(vals[3]) << 16);
            *(uint2*)((char*)alds[cur ^ 1] +
                      ASWZ(li, li * 256 + 32 * w + 8 * h)) = pkd;
            __syncthreads();
            cur ^= 1;
        }
    }

    // ---- final single step t = 8191: alpha @ A, * e_{obs[b][8191]} ----
    {
        bf16x8 bf[4];
#pragma unroll
        for (int q = 0; q < 4; ++q)
            bf[q] = *(const bf16x8*)((const char*)alds[cur] +
                    ASWZ(li, li * 256 + 64 * q + 16 * h));
        f32x4 acc = (f32x4){0.f, 0.f, 0.f, 0.f};
#pragma unroll
        for (int q = 0; q < 4; ++q) acc = MFMA(afin[q], bf[q], acc, 0, 0, 0);
        const int of = obs_lds[li][127];
        float sm = 0.f;
#pragma unroll
        for (int r = 0; r < 4; ++r) {
            float e = er[0][r];
            e = (of == 1) ? er[1][r] : e;
            e = (of == 2) ? er[2][r] : e;
            e = (of == 3) ? er[3][r] : e;
            e = (of == 4) ? er[4][r] : e;
            e = (of == 5) ? er[5][r] : e;
            sm += acc[r] * e;
        }
        sm += __shfl_xor(sm, 16);
        sm += __shfl_xor(sm, 32);
        if (l < 16) part[w][li] = sm;
        __syncthreads();
        if (tid < ROWS) {
            float Z = 0.f;
#pragma unroll
            for (int ww = 0; ww < WAVES; ++ww) Z += part[ww][tid];
            out[brow0 + tid] = ll + logf(Z);
        }
    }
}

// ---------------------------------------------------------------------------
// Fallback (round-7 kernel) if workspace is too small for Ct.
// ---------------------------------------------------------------------------
#define SWZ(r, c) ((((r) * NS) + (c)) ^ (((r) & 7) << 3))

__global__ void __launch_bounds__(256, 1)
hmm_gemm_kernel(const int* __restrict__ obs, const float* __restrict__ I,
                const float* __restrict__ A, const float* __restrict__ Bm,
                float* __restrict__ out)
{
    __shared__ __align__(16) ushort alds2[2][ROWS * NS];
    __shared__ float Bt[NE * NS];
    __shared__ __align__(16) int obs_lds[ROWS][132];
    __shared__ float part[4][ROWS];
    __shared__ float Zs[ROWS];

    const int tid = threadIdx.x;
    const int w   = tid >> 6;
    const int l   = tid & 63;
    const int h   = l >> 4;
    const int li  = l & 15;
    const int brow0 = blockIdx.x * ROWS;

    if (tid < NS) {
#pragma unroll
        for (int k = 0; k < NE; ++k) Bt[k * NS + tid] = Bm[tid * NE + k];
    }
    {
        const int r = tid >> 4, i0 = (tid & 15) * 8;
        const int32x4* g = (const int32x4*)(obs + (size_t)(brow0 + r) * NT + i0);
        *(int32x4*)&obs_lds[r][i0]     = g[0];
        *(int32x4*)&obs_lds[r][i0 + 4] = g[1];
    }
    bf16x8 bfrag[2][4];
#pragma unroll
    for (int tl = 0; tl < 2; ++tl) {
#pragma unroll
        for (int q = 0; q < 4; ++q) {
            const float* src = A + (size_t)(32 * q + 8 * h) * NS + (32 * w + 16 * tl + li);
            bf16x8 f;
#pragma unroll
            for (int j = 0; j < 8; ++j) f[j] = (short)f2bf(src[j * NS]);
            bfrag[tl][q] = f;
        }
    }
    __syncthreads();
    {
        const int r = tid >> 4, c0 = (tid & 15) * 8;
        const int o0 = obs_lds[r][0];
#pragma unroll
        for (int j = 0; j < 8; ++j) {
            const int c = c0 + j;
            alds2[0][SWZ(r, c)] = f2bf(I[c] * Bt[o0 * NS + c]);
        }
    }
    __syncthreads();

    float ll = 0.f;
    int cur = 0;
    for (int t = 1; t < NT; ++t) {
        if ((t & 127) == 0) {
            const int r = tid >> 4, i0 = (tid & 15) * 8;
            const int32x4* g = (const int32x4*)(obs + (size_t)(brow0 + r) * NT + t + i0);
            *(int32x4*)&obs_lds[r][i0]     = g[0];
            *(int32x4*)&obs_lds[r][i0 + 4] = g[1];
            __syncthreads();
        }
        bf16x8 af[4];
#pragma unroll
        for (int q = 0; q < 4; ++q)
            af[q] = *(const bf16x8*)&alds2[cur][SWZ(li, 32 * q + 8 * h)];
        const int tt = t & 127;
        int o[4];
#pragma unroll
        for (int r = 0; r < 4; ++r) o[r] = obs_lds[4 * h + r][tt];
        f32x4 acc[2];
        acc[0] = (f32x4){0.f, 0.f, 0.f, 0.f};
        acc[1] = (f32x4){0.f, 0.f, 0.f, 0.f};
#pragma unroll
        for (int q = 0; q < 4; ++q) {
            acc[0] = MFMA(af[q], bfrag[0][q], acc[0], 0, 0, 0);
            acc[1] = MFMA(af[q], bfrag[1][q], acc[1], 0, 0, 0);
        }
        float vals[2][4];
#pragma unroll
        for (int tl = 0; tl < 2; ++tl) {
            const int c = 32 * w + 16 * tl + li;
#pragma unroll
            for (int r = 0; r < 4; ++r) vals[tl][r] = acc[tl][r] * Bt[o[r] * NS + c];
        }
        const bool resc = ((t & 15) == 0) || (t == NT - 1);
        if (resc) {
#pragma unroll
            for (int r = 0; r < 4; ++r) {
                float s = vals[0][r] + vals[1][r];
#pragma unroll
                for (int off = 1; off < 16; off <<= 1) s += __shfl_xor(s, off);
                if (li == 0) part[w][4 * h + r] = s;
            }
            __syncthreads();
            if (tid < ROWS) {
                float Z = part[0][tid] + part[1][tid] + part[2][tid] + part[3][tid];
                ll += logf(Z);
                Zs[tid] = 1.0f / Z;
            }
            __syncthreads();
#pragma unroll
            for (int tl = 0; tl < 2; ++tl)
#pragma unroll
                for (int r = 0; r < 4; ++r) vals[tl][r] *= Zs[4 * h + r];
        }
#pragma unroll
        for (int tl = 0; tl < 2; ++tl) {
            const int c = 32 * w + 16 * tl + li;
#pragma unroll
            for (int r = 0; r < 4; ++r)
                alds2[cur ^ 1][SWZ(4 * h + r, c)] = f2bf(vals[tl][r]);
        }
        __syncthreads();
        cur ^= 1;
    }
    if (tid < ROWS) out[brow0 + tid] = ll;
}

extern "C" void kernel_launch(void* const* d_in, const int* in_sizes, int n_in,
                              void* d_out, int out_size, void* d_ws, size_t ws_size,
                              hipStream_t stream) {
    (void)in_sizes; (void)n_in; (void)out_size;
    const int*   obs = (const int*)d_in[0];
    const float* I   = (const float*)d_in[1];
    const float* A   = (const float*)d_in[2];
    const float* Bm  = (const float*)d_in[3];
    float*       out = (float*)d_out;

    if (ws_size < (size_t)CT_BYTES) {
        hipLaunchKernelGGL(hmm_gemm_kernel, dim3(NB / ROWS), dim3(256), 0, stream,
                           obs, I, A, Bm, out);
        return;
    }
    ushort* Ct = (ushort*)d_ws;
    hipLaunchKernelGGL(hmm_precompute_kernel, dim3(NMAT, 4), dim3(128), 0, stream,
                       A, Bm, Ct);
    hipLaunchKernelGGL(hmm_swap_kernel, dim3(NB / ROWS), dim3(512), 0, stream,
                       obs, I, Bm, Ct, out);
}